// Round 14
// baseline (2846.945 us; speedup 1.0000x reference)
//
#include <hip/hip_runtime.h>
#include <hip/hip_bf16.h>

// ---------------------------------------------------------------------------
// Mamba encoder fwd: B=2, L=1024, D=512, E=1024, N=16, R=32, 6 layers.
// R13: R12's merged scan (stage1+2+3, register/LDS carry across grid
// barriers) relaunched as a PLAIN kernel — hipLaunchCooperativeKernel was
// dropped by graph capture (R12 absmax blew up; R4 proved plain launch +
// manual agent-scope atomic barrier works under this harness). 512 blocks
// at launch_bounds(256,2) = exactly 2/CU x 256 CU = device capacity ->
// co-resident; TLP preserved. Everything else == R11 (758-760us).
// ---------------------------------------------------------------------------

typedef __attribute__((ext_vector_type(8))) short bf16x8;
typedef __attribute__((ext_vector_type(4))) float f32x4;

__device__ __forceinline__ float bf2f(unsigned short u) {
    unsigned int x = ((unsigned int)u) << 16;
    return __builtin_bit_cast(float, x);
}
__device__ __forceinline__ unsigned short f2bf(float f) {
    __hip_bfloat16 h = __float2bfloat16(f);   // RNE
    return __builtin_bit_cast(unsigned short, h);
}
__device__ __forceinline__ float ldin(const void* p, size_t i, int isbf) {
    return isbf ? bf2f(((const unsigned short*)p)[i]) : ((const float*)p)[i];
}
__device__ __forceinline__ float softplus_f(float x) {
    return (x > 20.f) ? x : log1pf(__expf(x));
}
__device__ __forceinline__ void split2(float x, unsigned short& h, unsigned short& l) {
    h = f2bf(x);
    l = f2bf(x - bf2f(h));   // == 0 when x is exactly bf16
}

// ---- device-wide barrier (monotone counter; R4-validated under graphs) -----
__device__ __forceinline__ void gsync(int* cnt, int target) {
    __syncthreads();
    __threadfence();
    if (threadIdx.x == 0) {
        __hip_atomic_fetch_add(cnt, 1, __ATOMIC_ACQ_REL, __HIP_MEMORY_SCOPE_AGENT);
        while (__hip_atomic_load(cnt, __ATOMIC_ACQUIRE, __HIP_MEMORY_SCOPE_AGENT) < target)
            __builtin_amdgcn_s_sleep(2);
    }
    __syncthreads();
    __threadfence();
}

// --------- all-weights prep (+ dtype flag publish), one kernel --------------
#define S1 (6*2048*512)
#define S2 (6*512*1024)
#define S3 (6*64*1024)
#define S4 (6*1024*32)
#define S5 (6*1024*16)
#define S6 (6*4*1024)
#define S7 (6*1024)
__global__ __launch_bounds__(256) void wsplit_all(
    const void* __restrict__ ipw, const void* __restrict__ ow,
    const void* __restrict__ xpw, const void* __restrict__ dtw,
    const void* __restrict__ alog, const void* __restrict__ cw,
    const void* __restrict__ cb, const void* __restrict__ Dw,
    unsigned short* __restrict__ h1, unsigned short* __restrict__ l1,
    unsigned short* __restrict__ h2, unsigned short* __restrict__ l2,
    unsigned short* __restrict__ h3, unsigned short* __restrict__ l3,
    float* __restrict__ dtwT, float* __restrict__ AenT,
    float* __restrict__ cwT, float* __restrict__ cbF,
    int* __restrict__ flag)
{
    int g = blockIdx.x * 256 + threadIdx.x;
    const int isbf = (*(const unsigned int*)Dw == 0x3F800000u) ? 0 : 1;
    if (g == 0) *flag = isbf;
    if (g < S1 + S2 + S3) {
        const void* src; unsigned short *dh, *dl; int i;
        if (g < S1)            { src = ipw; dh = h1; dl = l1; i = g; }
        else if (g < S1 + S2)  { src = ow;  dh = h2; dl = l2; i = g - S1; }
        else                   { src = xpw; dh = h3; dl = l3; i = g - S1 - S2; }
        unsigned short hh, ll;
        split2(ldin(src, i, isbf), hh, ll);
        dh[i] = hh; dl[i] = ll;
    } else if (g < S1 + S2 + S3 + S4) {
        int i = g - (S1 + S2 + S3);              // (l, e, k) -> (l, k, e)
        int l = i >> 15, rem = i & 32767;
        int e = rem >> 5, k = rem & 31;
        dtwT[(size_t)l * 32768 + k * 1024 + e] =
            ldin(dtw, (size_t)l * 32768 + e * 32 + k, isbf);
    } else if (g < S1 + S2 + S3 + S4 + S5) {
        int i = g - (S1 + S2 + S3 + S4);         // (l, e, n) -> (l, n, e)
        int l = i >> 14, rem = i & 16383;
        int n = rem >> 10, e = rem & 1023;
        AenT[(size_t)l * 16384 + n * 1024 + e] =
            -__expf(ldin(alog, (size_t)l * 16384 + e * 16 + n, isbf));
    } else if (g < S1 + S2 + S3 + S4 + S5 + S6) {
        int i = g - (S1 + S2 + S3 + S4 + S5);    // (l, e, k) -> (l, k, e)
        int l = i >> 12, rem = i & 4095;
        int k = rem >> 10, e = rem & 1023;
        cwT[(size_t)l * 4096 + k * 1024 + e] =
            ldin(cw, (size_t)l * 4096 + e * 4 + k, isbf);
    } else if (g < S1 + S2 + S3 + S4 + S5 + S6 + S7) {
        int i = g - (S1 + S2 + S3 + S4 + S5 + S6);
        cbF[i] = ldin(cb, i, isbf);
    }
}

// ------------------ GEMM 128x128 tile (in_proj): C = A * W^T ----------------
__global__ __launch_bounds__(512) void gemm128(
    const unsigned short* __restrict__ Ah, const unsigned short* __restrict__ Al,
    int lda,
    const unsigned short* __restrict__ Wh, const unsigned short* __restrict__ Wl,
    long woff,
    float* __restrict__ Cf, int N, int K)
{
    __shared__ __align__(16) unsigned short As[2][128][40];
    __shared__ __align__(16) unsigned short Ws[2][128][40];

    const int bid = blockIdx.x;
    const int xcd = bid & 7, s = bid >> 3;          // s in [0,32)
    const int mt = (xcd >> 1) * 4 + (s & 3);        // [0,16)
    const int nt = (xcd & 1) * 8 + (s >> 2);        // [0,16)
    const int m0 = mt * 128, n0 = nt * 128;

    const int t = threadIdx.x, lane = t & 63, wave = t >> 6;   // 0..7
    const int wm = (wave & 1) * 64, wn = (wave >> 1) * 32;
    const int srow = t >> 2, scol = (t & 3) * 8;

    const unsigned short* ah = Ah + (size_t)(m0 + srow) * lda + scol;
    const unsigned short* al = Al + (size_t)(m0 + srow) * lda + scol;
    const unsigned short* wh = Wh + woff + (size_t)(n0 + srow) * K + scol;
    const unsigned short* wl = Wl + woff + (size_t)(n0 + srow) * K + scol;

    f32x4 acc[4][2] = {};
    const int fm = lane & 15, fk = (lane >> 4) * 8;

    uint4 r0, r1, r2, r3;
#define LD128(K0) do { \
        r0 = *(const uint4*)(ah + (K0)); \
        r1 = *(const uint4*)(al + (K0)); \
        r2 = *(const uint4*)(wh + (K0)); \
        r3 = *(const uint4*)(wl + (K0)); \
    } while (0)
#define ST128() do { \
        *(uint4*)(&As[0][srow][scol]) = r0; \
        *(uint4*)(&As[1][srow][scol]) = r1; \
        *(uint4*)(&Ws[0][srow][scol]) = r2; \
        *(uint4*)(&Ws[1][srow][scol]) = r3; \
    } while (0)

    LD128(0);
    ST128();
    __syncthreads();

    for (int k0 = 0; k0 < K; k0 += 32) {
        const int more = (k0 + 32 < K);
        if (more) LD128(k0 + 32);            // issue next tile early

        bf16x8 a_h[4], a_l[4], w_h[2], w_l[2];
#pragma unroll
        for (int i = 0; i < 4; ++i) {
            a_h[i] = *(const bf16x8*)(&As[0][wm + i * 16 + fm][fk]);
            a_l[i] = *(const bf16x8*)(&As[1][wm + i * 16 + fm][fk]);
        }
#pragma unroll
        for (int j = 0; j < 2; ++j) {
            w_h[j] = *(const bf16x8*)(&Ws[0][wn + j * 16 + fm][fk]);
            w_l[j] = *(const bf16x8*)(&Ws[1][wn + j * 16 + fm][fk]);
        }
#pragma unroll
        for (int mi = 0; mi < 4; ++mi)
#pragma unroll
            for (int ni = 0; ni < 2; ++ni) {
                acc[mi][ni] = __builtin_amdgcn_mfma_f32_16x16x32_bf16(
                    a_h[mi], w_h[ni], acc[mi][ni], 0, 0, 0);
                acc[mi][ni] = __builtin_amdgcn_mfma_f32_16x16x32_bf16(
                    a_h[mi], w_l[ni], acc[mi][ni], 0, 0, 0);
                acc[mi][ni] = __builtin_amdgcn_mfma_f32_16x16x32_bf16(
                    a_l[mi], w_h[ni], acc[mi][ni], 0, 0, 0);
            }

        if (more) {
            __syncthreads();
            ST128();
            __syncthreads();
        }
    }
#undef LD128
#undef ST128

    const int col = lane & 15, rb = (lane >> 4) * 4;
#pragma unroll
    for (int mi = 0; mi < 4; ++mi)
#pragma unroll
        for (int ni = 0; ni < 2; ++ni)
#pragma unroll
            for (int r = 0; r < 4; ++r) {
                int gm = m0 + wm + mi * 16 + rb + r;
                int gn = n0 + wn + ni * 16 + col;
                Cf[(size_t)gm * N + gn] = acc[mi][ni][r];
            }
}

// ----------------------- GEMM 64x64 tile: C = A * W^T -----------------------
template <int ACT, int SWZ>
__global__ __launch_bounds__(512) void gemm_hl(
    const unsigned short* __restrict__ Ah, const unsigned short* __restrict__ Al,
    int lda,
    const unsigned short* __restrict__ Wh, const unsigned short* __restrict__ Wl,
    long woff,
    float* __restrict__ Cf, long zstride,
    const void* __restrict__ bias, long boff, const int* __restrict__ flag,
    int N, int K, int Kc)
{
    const int isbf = *flag;
    __shared__ __align__(16) unsigned short As[2][2][64][40];  // [dbuf][hl]
    __shared__ __align__(16) unsigned short Ws[2][2][64][40];

    int m0, n0, kb;
    if (SWZ) {
        const int bid = blockIdx.x;
        const int xcd = bid & 7, s = bid >> 3;     // s in [0,32)
        m0 = (xcd * 4 + (s & 3)) * 64;             // m-tile in [0,32)
        n0 = (s >> 2) * 64;                        // n-tile in [0,8)
        kb = 0;
    } else {
        m0 = blockIdx.x * 64; n0 = blockIdx.y * 64; kb = blockIdx.z * Kc;
    }
    const int t = threadIdx.x;
    const int lane = t & 63, wave = t >> 6;   // 0..7
    const int wm = (wave & 1) * 32, wn = (wave >> 1) * 16;
    const int u = t & 255;
    const int srow = u >> 2, scol = (u & 3) * 8;
    const int isA = (t < 256);

    const unsigned short* ph = isA ? (Ah + (size_t)(m0 + srow) * lda + scol)
                                   : (Wh + woff + (size_t)(n0 + srow) * K + scol);
    const unsigned short* pl = isA ? (Al + (size_t)(m0 + srow) * lda + scol)
                                   : (Wl + woff + (size_t)(n0 + srow) * K + scol);

    f32x4 acc[2] = {};

    uint4 r0, r1;
#define LD64(K0) do { \
        r0 = *(const uint4*)(ph + (K0)); \
        r1 = *(const uint4*)(pl + (K0)); \
    } while (0)
#define ST64(B) do { \
        if (isA) { \
            *(uint4*)(&As[B][0][srow][scol]) = r0; \
            *(uint4*)(&As[B][1][srow][scol]) = r1; \
        } else { \
            *(uint4*)(&Ws[B][0][srow][scol]) = r0; \
            *(uint4*)(&Ws[B][1][srow][scol]) = r1; \
        } \
    } while (0)

    LD64(kb);
    ST64(0);
    __syncthreads();

    int cur = 0;
    for (int k0 = kb; k0 < kb + Kc; k0 += 32) {
        const int more = (k0 + 32 < kb + Kc);
        if (more) LD64(k0 + 32);

        const int fm = lane & 15, fk = (lane >> 4) * 8;
        bf16x8 a0h = *(const bf16x8*)(&As[cur][0][wm + fm][fk]);
        bf16x8 a1h = *(const bf16x8*)(&As[cur][0][wm + 16 + fm][fk]);
        bf16x8 a0l = *(const bf16x8*)(&As[cur][1][wm + fm][fk]);
        bf16x8 a1l = *(const bf16x8*)(&As[cur][1][wm + 16 + fm][fk]);
        bf16x8 w0h = *(const bf16x8*)(&Ws[cur][0][wn + fm][fk]);
        bf16x8 w0l = *(const bf16x8*)(&Ws[cur][1][wn + fm][fk]);

        acc[0] = __builtin_amdgcn_mfma_f32_16x16x32_bf16(a0h, w0h, acc[0], 0, 0, 0);
        acc[1] = __builtin_amdgcn_mfma_f32_16x16x32_bf16(a1h, w0h, acc[1], 0, 0, 0);
        acc[0] = __builtin_amdgcn_mfma_f32_16x16x32_bf16(a0h, w0l, acc[0], 0, 0, 0);
        acc[1] = __builtin_amdgcn_mfma_f32_16x16x32_bf16(a1h, w0l, acc[1], 0, 0, 0);
        acc[0] = __builtin_amdgcn_mfma_f32_16x16x32_bf16(a0l, w0h, acc[0], 0, 0, 0);
        acc[1] = __builtin_amdgcn_mfma_f32_16x16x32_bf16(a1l, w0h, acc[1], 0, 0, 0);

        if (more) {
            ST64(cur ^ 1);          // safe: buf[cur^1] readers fenced last iter
            __syncthreads();        // stores visible before next-iter reads
            cur ^= 1;
        }
    }
#undef LD64
#undef ST64

    float* Cp = Cf + (size_t)blockIdx.z * zstride;
    const int col = lane & 15, rb = (lane >> 4) * 4;
#pragma unroll
    for (int mi = 0; mi < 2; ++mi)
#pragma unroll
        for (int r = 0; r < 4; ++r) {
            int gm = m0 + wm + mi * 16 + rb + r;
            int gn = n0 + wn + col;
            float v = acc[mi][r];
            if (bias) v += ldin(bias, boff + gn, isbf);
            if (ACT == 1) v = softplus_f(v);
            Cp[(size_t)gm * N + gn] = v;
        }
}

// ------------------- RMSNorm(h + pos) -> pre-split bf16 ---------------------
__global__ __launch_bounds__(256) void rmsnorm_k(
    const void* __restrict__ hsrc, int hdyn, const void* __restrict__ pos,
    const void* __restrict__ nw, const int* __restrict__ flag,
    unsigned short* __restrict__ xnh, unsigned short* __restrict__ xnl)
{
    const int isbf = *flag;
    const int row = blockIdx.x;
    const int t = threadIdx.x;
    const size_t base = (size_t)row * 512;
    float h0 = hdyn ? ldin(hsrc, base + t, isbf)       : ((const float*)hsrc)[base + t];
    float h1 = hdyn ? ldin(hsrc, base + 256 + t, isbf) : ((const float*)hsrc)[base + 256 + t];
    float v0 = h0 + ldin(pos, base + t, isbf);
    float v1 = h1 + ldin(pos, base + 256 + t, isbf);
    float ss = v0 * v0 + v1 * v1;
#pragma unroll
    for (int o = 32; o; o >>= 1) ss += __shfl_xor(ss, o, 64);
    __shared__ float sw[4];
    if ((t & 63) == 0) sw[t >> 6] = ss;
    __syncthreads();
    float tot = sw[0] + sw[1] + sw[2] + sw[3];
    float sc = rsqrtf(tot * (1.0f / 512.0f) + 1.1920929e-07f);
    float o0 = v0 * sc * ldin(nw, t, isbf);
    float o1 = v1 * sc * ldin(nw, 256 + t, isbf);
    unsigned short hh, ll;
    split2(o0, hh, ll); xnh[base + t] = hh;       xnl[base + t] = ll;
    split2(o1, hh, ll); xnh[base + 256 + t] = hh; xnl[base + 256 + t] = ll;
}

// ------- causal depthwise conv (k=4) + SiLU -> fp32 u + pre-split bf16 ------
__global__ __launch_bounds__(256) void conv_silu_k(
    const float* __restrict__ xz,
    const float* __restrict__ cwT, long cwoff,
    const float* __restrict__ cbF, long cboff,
    float* __restrict__ xi,
    unsigned short* __restrict__ xih, unsigned short* __restrict__ xil)
{
    int g = blockIdx.x * 256 + threadIdx.x;   // T*E = 2M
    int e = g & 1023;
    int l = (g >> 10) & 1023;
    int b = g >> 20;
    float acc = cbF[cboff + e];
#pragma unroll
    for (int k = 0; k < 4; ++k) {
        int ls = l - 3 + k;
        if (ls >= 0)
            acc += cwT[cwoff + k * 1024 + e] *
                   xz[((size_t)(b * 1024 + ls)) * 2048 + e];
    }
    acc = acc / (1.f + __expf(-acc));         // SiLU
    xi[g] = acc;
    unsigned short hh, ll;
    split2(acc, hh, ll);
    xih[g] = hh; xil[g] = ll;
}

// ------------- merged selective scan: stage1 + stage2 + stage3 --------------
#define CL 16
#define NCH 64

struct ScanP {
    const float* Pxp;
    const float* dtwT; long dtwoff;
    const void* dtb;  long dtboff;
    const float* AenT; long aoff;
    const float* xi;
    const float* xz;
    const void* Dv;   long doff;
    const int* flag;
    float* S; float* Dsum; float* H0;
    unsigned short* yh; unsigned short* yl;
    int* bar; int ep0;
};

// 512 blocks x 256 threads at launch_bounds(256,2): exactly 2 blocks/CU x
// 256 CUs = grid size -> co-resident by capacity (R4-proven barrier works).
__global__ __launch_bounds__(256, 2) void scan_all(ScanP p)
{
    const int isbf = *p.flag;
    const int tid = threadIdx.x;
    const int bid = blockIdx.x;               // [0,512)
    const int eg = bid & 3, c = (bid >> 2) & 63, b = bid >> 8;
    const int e = eg * 256 + tid;
    const int t0 = b * 1024 + c * CL;

    __shared__ float red[CL][64];             // chunk's dbc rows (persists)

    // ---- phase 1: split-K reduce + dt(fp32) + chunk scan ----
    for (int idx = tid; idx < CL * 64; idx += 256) {
        int ti = idx >> 6, n = idx & 63;
        float s = 0.f;
#pragma unroll
        for (int z = 0; z < 8; ++z)
            s += p.Pxp[(size_t)z * 131072 + (size_t)(t0 + ti) * 64 + n];
        red[ti][n] = s;
    }

    float wk[32];
#pragma unroll
    for (int k = 0; k < 32; ++k) wk[k] = p.dtwT[p.dtwoff + (size_t)k * 1024 + e];
    const float bias = ldin(p.dtb, p.dtboff + e, isbf);
    float Aen[16];
#pragma unroll
    for (int n = 0; n < 16; ++n) Aen[n] = p.AenT[p.aoff + (size_t)n * 1024 + e];
    float uv[CL];
#pragma unroll
    for (int i = 0; i < CL; ++i) uv[i] = p.xi[(size_t)(t0 + i) * 1024 + e];

    __syncthreads();

    float dv[CL];                             // register-carried to phase 3
    float Sn[16];
#pragma unroll
    for (int n = 0; n < 16; ++n) Sn[n] = 0.f;
    float ds = 0.f;
#pragma unroll
    for (int i = 0; i < CL; ++i) {
        const float4* rp = (const float4*)&red[i][0];
        float acc = bias;
#pragma unroll
        for (int k4 = 0; k4 < 8; ++k4) {
            float4 r4 = rp[k4];
            acc += r4.x * wk[k4 * 4 + 0] + r4.y * wk[k4 * 4 + 1]
                 + r4.z * wk[k4 * 4 + 2] + r4.w * wk[k4 * 4 + 3];
        }
        float d = softplus_f(acc);
        dv[i] = d;
        ds += d;
        float du = d * uv[i];
        const float4* Bp = (const float4*)&red[i][32];
        float4 b0 = Bp[0], b1 = Bp[1], b2 = Bp[2], b3 = Bp[3];
        float Bt[16] = {b0.x,b0.y,b0.z,b0.w, b1.x,b1.y,b1.z,b1.w,
                        b2.x,b2.y,b2.z,b2.w, b3.x,b3.y,b3.z,b3.w};
#pragma unroll
        for (int n = 0; n < 16; ++n) {
            float a = __expf(d * Aen[n]);
            Sn[n] = a * Sn[n] + du * Bt[n];
        }
    }
    size_t ob = ((size_t)(b * NCH + c) * 16) * 1024 + e;
#pragma unroll
    for (int n = 0; n < 16; ++n) p.S[ob + (size_t)n * 1024] = Sn[n];
    p.Dsum[(size_t)(b * NCH + c) * 1024 + e] = ds;

    gsync(p.bar, (p.ep0 + 1) * 512);

    // ---- phase 2: cross-chunk combine (blocks 0..127 only) ----
    if (bid < 128) {
        int g = bid * 256 + tid;              // 32768: e + 1024n + 16384b
        int e2 = g & 1023, n2 = (g >> 10) & 15, b2 = g >> 14;
        const float Aen2 = p.AenT[p.aoff + (size_t)n2 * 1024 + e2];
        float H = 0.f;
        for (int cb = 0; cb < NCH; cb += 8) {
            float s[8], pj[8];
#pragma unroll
            for (int j = 0; j < 8; ++j) {
                size_t idx = ((size_t)(b2 * NCH + cb + j) * 16 + n2) * 1024 + e2;
                s[j] = p.S[idx];
                pj[j] = __expf(p.Dsum[(size_t)(b2 * NCH + cb + j) * 1024 + e2] * Aen2);
            }
#pragma unroll
            for (int j = 0; j < 8; ++j) {
                size_t idx = ((size_t)(b2 * NCH + cb + j) * 16 + n2) * 1024 + e2;
                p.H0[idx] = H;
                H = pj[j] * H + s[j];
            }
        }
    }

    gsync(p.bar, (p.ep0 + 2) * 512);

    // ---- phase 3: final sweep (dv/uv/Aen in regs, B/C rows in LDS red) ----
    float zv[CL];
#pragma unroll
    for (int i = 0; i < CL; ++i)
        zv[i] = p.xz[(size_t)(t0 + i) * 2048 + 1024 + e];
    float hS[16];
#pragma unroll
    for (int n = 0; n < 16; ++n) hS[n] = p.H0[ob + (size_t)n * 1024];
    float De = ldin(p.Dv, p.doff + e, isbf);
#pragma unroll
    for (int i = 0; i < CL; ++i) {
        float d = dv[i], uu = uv[i], du = d * uu;
        const float4* Bp = (const float4*)&red[i][32];
        float4 b0 = Bp[0], b1 = Bp[1], b2 = Bp[2], b3 = Bp[3];
        float4 c0 = Bp[4], c1 = Bp[5], c2 = Bp[6], c3 = Bp[7];
        float Bt[16] = {b0.x,b0.y,b0.z,b0.w, b1.x,b1.y,b1.z,b1.w,
                        b2.x,b2.y,b2.z,b2.w, b3.x,b3.y,b3.z,b3.w};
        float Ct[16] = {c0.x,c0.y,c0.z,c0.w, c1.x,c1.y,c1.z,c1.w,
                        c2.x,c2.y,c2.z,c2.w, c3.x,c3.y,c3.z,c3.w};
        float y = 0.f;
#pragma unroll
        for (int n = 0; n < 16; ++n) {
            float a = __expf(d * Aen[n]);
            hS[n] = a * hS[n] + du * Bt[n];
            y += hS[n] * Ct[n];
        }
        float sz = zv[i] / (1.f + __expf(-zv[i]));
        float yv = (y + uu * De) * sz;
        unsigned short hh, ll;
        split2(yv, hh, ll);
        p.yh[(size_t)(t0 + i) * 1024 + e] = hh;
        p.yl[(size_t)(t0 + i) * 1024 + e] = ll;
    }
}

__global__ void init_bar(int* bar) { *bar = 0; }

// ------------------------------- launcher -----------------------------------
extern "C" void kernel_launch(void* const* d_in, const int* in_sizes, int n_in,
                              void* d_out, int out_size, void* d_ws, size_t ws_size,
                              hipStream_t stream)
{
    const void* x    = d_in[0];
    const void* pos  = d_in[1];
    const void* nw   = d_in[2];
    const void* ipw  = d_in[3];   // (6,2048,512)
    const void* cw   = d_in[4];   // (6,1024,4)
    const void* cb   = d_in[5];   // (6,1024)
    const void* xpw  = d_in[6];   // (6,64,1024)
    const void* dtw  = d_in[7];   // (6,1024,32)
    const void* dtb  = d_in[8];   // (6,1024)
    const void* alog = d_in[9];   // (6,1024,16)
    const void* Dw   = d_in[10];  // (6,1024)
    const void* ow   = d_in[11];  // (6,512,1024)

    char* w = (char*)d_ws;
    auto take = [&](size_t bytes) { char* p = w; w += (bytes + 255) & ~255ull; return p; };

    float* h    = (float*)take(2048ull * 512 * 4);
    float* xz   = (float*)take(2048ull * 2048 * 4);
    float* xi   = (float*)take(2048ull * 1024 * 4);
    float* S    = (float*)take(2ull * NCH * 16 * 1024 * 4);   // 8 MB
    float* H0   = (float*)take(2ull * NCH * 16 * 1024 * 4);   // 8 MB
    float* Dsum = (float*)take(2ull * NCH * 1024 * 4);        // 0.5 MB
    float* Pxp  = (float*)take(8ull * 2048 * 64 * 4);
    float* dtwT = (float*)take(6ull * 32 * 1024 * 4);
    float* AenT = (float*)take(6ull * 16 * 1024 * 4);
    float* cwT  = (float*)take(6ull * 4 * 1024 * 4);
    float* cbF  = (float*)take(6ull * 1024 * 4);
    unsigned short* xnh = (unsigned short*)take(2048ull * 512 * 2);
    unsigned short* xnl = (unsigned short*)take(2048ull * 512 * 2);
    unsigned short* xih = (unsigned short*)take(2048ull * 1024 * 2);
    unsigned short* xil = (unsigned short*)take(2048ull * 1024 * 2);
    unsigned short* yh  = (unsigned short*)take(2048ull * 1024 * 2);
    unsigned short* yl  = (unsigned short*)take(2048ull * 1024 * 2);
    unsigned short* wip_h = (unsigned short*)take(6ull * 2048 * 512 * 2);
    unsigned short* wip_l = (unsigned short*)take(6ull * 2048 * 512 * 2);
    unsigned short* wow_h = (unsigned short*)take(6ull * 512 * 1024 * 2);
    unsigned short* wow_l = (unsigned short*)take(6ull * 512 * 1024 * 2);
    unsigned short* wxp_h = (unsigned short*)take(6ull * 64 * 1024 * 2);
    unsigned short* wxp_l = (unsigned short*)take(6ull * 64 * 1024 * 2);
    int* flag = (int*)take(256);
    int* bar  = (int*)take(256);

    init_bar<<<1, 1, 0, stream>>>(bar);
    wsplit_all<<<(S1 + S2 + S3 + S4 + S5 + S6 + S7 + 255) / 256, 256, 0, stream>>>(
        ipw, ow, xpw, dtw, alog, cw, cb, Dw,
        wip_h, wip_l, wow_h, wow_l, wxp_h, wxp_l, dtwT, AenT, cwT, cbF, flag);

    for (int l = 0; l < 6; ++l) {
        // rmsnorm(h + pos): layer 0 reads x (dynamic dtype), else fp32 h
        rmsnorm_k<<<2048, 256, 0, stream>>>(
            l == 0 ? x : (const void*)h, l == 0 ? 1 : 0, pos, nw, flag, xnh, xnl);
        // in_proj: 128x128 tiles, 8 waves, XCD-swizzled 1D grid
        gemm128<<<256, 512, 0, stream>>>(
            xnh, xnl, 512, wip_h, wip_l, (long)l * 2048 * 512, xz, 2048, 512);
        conv_silu_k<<<8192, 256, 0, stream>>>(xz, cwT, (long)l * 4096, cbF, (long)l * 1024,
                                              xi, xih, xil);
        // x_proj: (T,1024) x (64,1024)^T, split-K x8 -> Pxp, 8 waves, dbuf
        gemm_hl<0, 0><<<dim3(32, 1, 8), 512, 0, stream>>>(
            xih, xil, 1024, wxp_h, wxp_l, (long)l * 64 * 1024,
            Pxp, 2048l * 64, nullptr, 0, flag, 64, 1024, 128);
        // merged scan (stage1+2+3): plain launch, manual grid barriers.
        // 512 blocks @ 2/CU = device capacity -> co-resident.
        ScanP sp;
        sp.Pxp = Pxp;
        sp.dtwT = dtwT; sp.dtwoff = (long)l * 32768;
        sp.dtb = dtb;   sp.dtboff = (long)l * 1024;
        sp.AenT = AenT; sp.aoff = (long)l * 16384;
        sp.xi = xi; sp.xz = xz;
        sp.Dv = Dw; sp.doff = (long)l * 1024;
        sp.flag = flag;
        sp.S = S; sp.Dsum = Dsum; sp.H0 = H0;
        sp.yh = yh; sp.yl = yl;
        sp.bar = bar; sp.ep0 = 2 * l;
        scan_all<<<512, 256, 0, stream>>>(sp);
        // out_proj: 8 waves, dbuf, XCD-swizzled 1D grid (32m x 8n tiles)
        float* outp = (l < 5) ? h : (float*)d_out;
        gemm_hl<0, 1><<<256, 512, 0, stream>>>(
            yh, yl, 1024, wow_h, wow_l, (long)l * 512 * 1024,
            outp, 0, nullptr, 0, flag, 512, 1024, 1024);
    }
}

// Round 15
// 758.258 us; speedup vs baseline: 3.7546x; 3.7546x over previous
//
#include <hip/hip_runtime.h>
#include <hip/hip_bf16.h>

// ---------------------------------------------------------------------------
// Mamba encoder fwd: B=2, L=1024, D=512, E=1024, N=16, R=32, 6 layers.
// R14: revert to R11 (758.0us proven best). R13's merged scan was CORRECT but
// the manual grid barrier cost ~150us/barrier (512 waves spinning on one
// agent-scope cacheline across 8 XCDs) -> scan_all 405us vs 25us for the 3
// split kernels. Barrier-based fusion falsified on this chip/harness.
// Final structure: 8-wave GEMMs (128² 2-phase, 64² dbuf), fused
// xp_reduce+dt+scan1, Dsum trick, coalesced dtwT/AenT/cwT layouts, XCD
// swizzle (neutral/harmless). 865 -> 758us across the session.
// ---------------------------------------------------------------------------

typedef __attribute__((ext_vector_type(8))) short bf16x8;
typedef __attribute__((ext_vector_type(4))) float f32x4;

__device__ __forceinline__ float bf2f(unsigned short u) {
    unsigned int x = ((unsigned int)u) << 16;
    return __builtin_bit_cast(float, x);
}
__device__ __forceinline__ unsigned short f2bf(float f) {
    __hip_bfloat16 h = __float2bfloat16(f);   // RNE
    return __builtin_bit_cast(unsigned short, h);
}
__device__ __forceinline__ float ldin(const void* p, size_t i, int isbf) {
    return isbf ? bf2f(((const unsigned short*)p)[i]) : ((const float*)p)[i];
}
__device__ __forceinline__ float softplus_f(float x) {
    return (x > 20.f) ? x : log1pf(__expf(x));
}
__device__ __forceinline__ void split2(float x, unsigned short& h, unsigned short& l) {
    h = f2bf(x);
    l = f2bf(x - bf2f(h));   // == 0 when x is exactly bf16
}

// --------- all-weights prep (+ dtype flag publish), one kernel --------------
#define S1 (6*2048*512)
#define S2 (6*512*1024)
#define S3 (6*64*1024)
#define S4 (6*1024*32)
#define S5 (6*1024*16)
#define S6 (6*4*1024)
#define S7 (6*1024)
__global__ __launch_bounds__(256) void wsplit_all(
    const void* __restrict__ ipw, const void* __restrict__ ow,
    const void* __restrict__ xpw, const void* __restrict__ dtw,
    const void* __restrict__ alog, const void* __restrict__ cw,
    const void* __restrict__ cb, const void* __restrict__ Dw,
    unsigned short* __restrict__ h1, unsigned short* __restrict__ l1,
    unsigned short* __restrict__ h2, unsigned short* __restrict__ l2,
    unsigned short* __restrict__ h3, unsigned short* __restrict__ l3,
    float* __restrict__ dtwT, float* __restrict__ AenT,
    float* __restrict__ cwT, float* __restrict__ cbF,
    int* __restrict__ flag)
{
    int g = blockIdx.x * 256 + threadIdx.x;
    const int isbf = (*(const unsigned int*)Dw == 0x3F800000u) ? 0 : 1;
    if (g == 0) *flag = isbf;
    if (g < S1 + S2 + S3) {
        const void* src; unsigned short *dh, *dl; int i;
        if (g < S1)            { src = ipw; dh = h1; dl = l1; i = g; }
        else if (g < S1 + S2)  { src = ow;  dh = h2; dl = l2; i = g - S1; }
        else                   { src = xpw; dh = h3; dl = l3; i = g - S1 - S2; }
        unsigned short hh, ll;
        split2(ldin(src, i, isbf), hh, ll);
        dh[i] = hh; dl[i] = ll;
    } else if (g < S1 + S2 + S3 + S4) {
        int i = g - (S1 + S2 + S3);              // (l, e, k) -> (l, k, e)
        int l = i >> 15, rem = i & 32767;
        int e = rem >> 5, k = rem & 31;
        dtwT[(size_t)l * 32768 + k * 1024 + e] =
            ldin(dtw, (size_t)l * 32768 + e * 32 + k, isbf);
    } else if (g < S1 + S2 + S3 + S4 + S5) {
        int i = g - (S1 + S2 + S3 + S4);         // (l, e, n) -> (l, n, e)
        int l = i >> 14, rem = i & 16383;
        int n = rem >> 10, e = rem & 1023;
        AenT[(size_t)l * 16384 + n * 1024 + e] =
            -__expf(ldin(alog, (size_t)l * 16384 + e * 16 + n, isbf));
    } else if (g < S1 + S2 + S3 + S4 + S5 + S6) {
        int i = g - (S1 + S2 + S3 + S4 + S5);    // (l, e, k) -> (l, k, e)
        int l = i >> 12, rem = i & 4095;
        int k = rem >> 10, e = rem & 1023;
        cwT[(size_t)l * 4096 + k * 1024 + e] =
            ldin(cw, (size_t)l * 4096 + e * 4 + k, isbf);
    } else if (g < S1 + S2 + S3 + S4 + S5 + S6 + S7) {
        int i = g - (S1 + S2 + S3 + S4 + S5 + S6);
        cbF[i] = ldin(cb, i, isbf);
    }
}

// ------------------ GEMM 128x128 tile (in_proj): C = A * W^T ----------------
// 512 threads = 8 waves, each computing 64x32. 1D grid of 256 with XCD-aware
// decode: xcd = bid&7 owns a 4m x 8n region of the 16x16 tile grid.
__global__ __launch_bounds__(512) void gemm128(
    const unsigned short* __restrict__ Ah, const unsigned short* __restrict__ Al,
    int lda,
    const unsigned short* __restrict__ Wh, const unsigned short* __restrict__ Wl,
    long woff,
    float* __restrict__ Cf, int N, int K)
{
    __shared__ __align__(16) unsigned short As[2][128][40];
    __shared__ __align__(16) unsigned short Ws[2][128][40];

    const int bid = blockIdx.x;
    const int xcd = bid & 7, s = bid >> 3;          // s in [0,32)
    const int mt = (xcd >> 1) * 4 + (s & 3);        // [0,16)
    const int nt = (xcd & 1) * 8 + (s >> 2);        // [0,16)
    const int m0 = mt * 128, n0 = nt * 128;

    const int t = threadIdx.x, lane = t & 63, wave = t >> 6;   // 0..7
    const int wm = (wave & 1) * 64, wn = (wave >> 1) * 32;
    const int srow = t >> 2, scol = (t & 3) * 8;

    const unsigned short* ah = Ah + (size_t)(m0 + srow) * lda + scol;
    const unsigned short* al = Al + (size_t)(m0 + srow) * lda + scol;
    const unsigned short* wh = Wh + woff + (size_t)(n0 + srow) * K + scol;
    const unsigned short* wl = Wl + woff + (size_t)(n0 + srow) * K + scol;

    f32x4 acc[4][2] = {};
    const int fm = lane & 15, fk = (lane >> 4) * 8;

    uint4 r0, r1, r2, r3;
#define LD128(K0) do { \
        r0 = *(const uint4*)(ah + (K0)); \
        r1 = *(const uint4*)(al + (K0)); \
        r2 = *(const uint4*)(wh + (K0)); \
        r3 = *(const uint4*)(wl + (K0)); \
    } while (0)
#define ST128() do { \
        *(uint4*)(&As[0][srow][scol]) = r0; \
        *(uint4*)(&As[1][srow][scol]) = r1; \
        *(uint4*)(&Ws[0][srow][scol]) = r2; \
        *(uint4*)(&Ws[1][srow][scol]) = r3; \
    } while (0)

    LD128(0);
    ST128();
    __syncthreads();

    for (int k0 = 0; k0 < K; k0 += 32) {
        const int more = (k0 + 32 < K);
        if (more) LD128(k0 + 32);            // issue next tile early

        bf16x8 a_h[4], a_l[4], w_h[2], w_l[2];
#pragma unroll
        for (int i = 0; i < 4; ++i) {
            a_h[i] = *(const bf16x8*)(&As[0][wm + i * 16 + fm][fk]);
            a_l[i] = *(const bf16x8*)(&As[1][wm + i * 16 + fm][fk]);
        }
#pragma unroll
        for (int j = 0; j < 2; ++j) {
            w_h[j] = *(const bf16x8*)(&Ws[0][wn + j * 16 + fm][fk]);
            w_l[j] = *(const bf16x8*)(&Ws[1][wn + j * 16 + fm][fk]);
        }
#pragma unroll
        for (int mi = 0; mi < 4; ++mi)
#pragma unroll
            for (int ni = 0; ni < 2; ++ni) {
                acc[mi][ni] = __builtin_amdgcn_mfma_f32_16x16x32_bf16(
                    a_h[mi], w_h[ni], acc[mi][ni], 0, 0, 0);
                acc[mi][ni] = __builtin_amdgcn_mfma_f32_16x16x32_bf16(
                    a_h[mi], w_l[ni], acc[mi][ni], 0, 0, 0);
                acc[mi][ni] = __builtin_amdgcn_mfma_f32_16x16x32_bf16(
                    a_l[mi], w_h[ni], acc[mi][ni], 0, 0, 0);
            }

        if (more) {
            __syncthreads();
            ST128();
            __syncthreads();
        }
    }
#undef LD128
#undef ST128

    const int col = lane & 15, rb = (lane >> 4) * 4;
#pragma unroll
    for (int mi = 0; mi < 4; ++mi)
#pragma unroll
        for (int ni = 0; ni < 2; ++ni)
#pragma unroll
            for (int r = 0; r < 4; ++r) {
                int gm = m0 + wm + mi * 16 + rb + r;
                int gn = n0 + wn + ni * 16 + col;
                Cf[(size_t)gm * N + gn] = acc[mi][ni][r];
            }
}

// ----------------------- GEMM 64x64 tile: C = A * W^T -----------------------
// 512 threads = 8 waves, each 32x16 out. LDS double-buffered (1 barrier/step).
// SWZ=1 (out_proj): 1D grid 256, XCD r owns m-tiles [4r,4r+4) x all 8 n-tiles.
template <int ACT, int SWZ>
__global__ __launch_bounds__(512) void gemm_hl(
    const unsigned short* __restrict__ Ah, const unsigned short* __restrict__ Al,
    int lda,
    const unsigned short* __restrict__ Wh, const unsigned short* __restrict__ Wl,
    long woff,
    float* __restrict__ Cf, long zstride,
    const void* __restrict__ bias, long boff, const int* __restrict__ flag,
    int N, int K, int Kc)
{
    const int isbf = *flag;
    __shared__ __align__(16) unsigned short As[2][2][64][40];  // [dbuf][hl]
    __shared__ __align__(16) unsigned short Ws[2][2][64][40];

    int m0, n0, kb;
    if (SWZ) {
        const int bid = blockIdx.x;
        const int xcd = bid & 7, s = bid >> 3;     // s in [0,32)
        m0 = (xcd * 4 + (s & 3)) * 64;             // m-tile in [0,32)
        n0 = (s >> 2) * 64;                        // n-tile in [0,8)
        kb = 0;
    } else {
        m0 = blockIdx.x * 64; n0 = blockIdx.y * 64; kb = blockIdx.z * Kc;
    }
    const int t = threadIdx.x;
    const int lane = t & 63, wave = t >> 6;   // 0..7
    const int wm = (wave & 1) * 32, wn = (wave >> 1) * 16;
    const int u = t & 255;
    const int srow = u >> 2, scol = (u & 3) * 8;
    const int isA = (t < 256);

    const unsigned short* ph = isA ? (Ah + (size_t)(m0 + srow) * lda + scol)
                                   : (Wh + woff + (size_t)(n0 + srow) * K + scol);
    const unsigned short* pl = isA ? (Al + (size_t)(m0 + srow) * lda + scol)
                                   : (Wl + woff + (size_t)(n0 + srow) * K + scol);

    f32x4 acc[2] = {};

    uint4 r0, r1;
#define LD64(K0) do { \
        r0 = *(const uint4*)(ph + (K0)); \
        r1 = *(const uint4*)(pl + (K0)); \
    } while (0)
#define ST64(B) do { \
        if (isA) { \
            *(uint4*)(&As[B][0][srow][scol]) = r0; \
            *(uint4*)(&As[B][1][srow][scol]) = r1; \
        } else { \
            *(uint4*)(&Ws[B][0][srow][scol]) = r0; \
            *(uint4*)(&Ws[B][1][srow][scol]) = r1; \
        } \
    } while (0)

    LD64(kb);
    ST64(0);
    __syncthreads();

    int cur = 0;
    for (int k0 = kb; k0 < kb + Kc; k0 += 32) {
        const int more = (k0 + 32 < kb + Kc);
        if (more) LD64(k0 + 32);

        const int fm = lane & 15, fk = (lane >> 4) * 8;
        bf16x8 a0h = *(const bf16x8*)(&As[cur][0][wm + fm][fk]);
        bf16x8 a1h = *(const bf16x8*)(&As[cur][0][wm + 16 + fm][fk]);
        bf16x8 a0l = *(const bf16x8*)(&As[cur][1][wm + fm][fk]);
        bf16x8 a1l = *(const bf16x8*)(&As[cur][1][wm + 16 + fm][fk]);
        bf16x8 w0h = *(const bf16x8*)(&Ws[cur][0][wn + fm][fk]);
        bf16x8 w0l = *(const bf16x8*)(&Ws[cur][1][wn + fm][fk]);

        acc[0] = __builtin_amdgcn_mfma_f32_16x16x32_bf16(a0h, w0h, acc[0], 0, 0, 0);
        acc[1] = __builtin_amdgcn_mfma_f32_16x16x32_bf16(a1h, w0h, acc[1], 0, 0, 0);
        acc[0] = __builtin_amdgcn_mfma_f32_16x16x32_bf16(a0h, w0l, acc[0], 0, 0, 0);
        acc[1] = __builtin_amdgcn_mfma_f32_16x16x32_bf16(a1h, w0l, acc[1], 0, 0, 0);
        acc[0] = __builtin_amdgcn_mfma_f32_16x16x32_bf16(a0l, w0h, acc[0], 0, 0, 0);
        acc[1] = __builtin_amdgcn_mfma_f32_16x16x32_bf16(a1l, w0h, acc[1], 0, 0, 0);

        if (more) {
            ST64(cur ^ 1);          // safe: buf[cur^1] readers fenced last iter
            __syncthreads();        // stores visible before next-iter reads
            cur ^= 1;
        }
    }
#undef LD64
#undef ST64

    float* Cp = Cf + (size_t)blockIdx.z * zstride;
    const int col = lane & 15, rb = (lane >> 4) * 4;
#pragma unroll
    for (int mi = 0; mi < 2; ++mi)
#pragma unroll
        for (int r = 0; r < 4; ++r) {
            int gm = m0 + wm + mi * 16 + rb + r;
            int gn = n0 + wn + col;
            float v = acc[mi][r];
            if (bias) v += ldin(bias, boff + gn, isbf);
            if (ACT == 1) v = softplus_f(v);
            Cp[(size_t)gm * N + gn] = v;
        }
}

// ------------------- RMSNorm(h + pos) -> pre-split bf16 ---------------------
__global__ __launch_bounds__(256) void rmsnorm_k(
    const void* __restrict__ hsrc, int hdyn, const void* __restrict__ pos,
    const void* __restrict__ nw, const int* __restrict__ flag,
    unsigned short* __restrict__ xnh, unsigned short* __restrict__ xnl)
{
    const int isbf = *flag;
    const int row = blockIdx.x;
    const int t = threadIdx.x;
    const size_t base = (size_t)row * 512;
    float h0 = hdyn ? ldin(hsrc, base + t, isbf)       : ((const float*)hsrc)[base + t];
    float h1 = hdyn ? ldin(hsrc, base + 256 + t, isbf) : ((const float*)hsrc)[base + 256 + t];
    float v0 = h0 + ldin(pos, base + t, isbf);
    float v1 = h1 + ldin(pos, base + 256 + t, isbf);
    float ss = v0 * v0 + v1 * v1;
#pragma unroll
    for (int o = 32; o; o >>= 1) ss += __shfl_xor(ss, o, 64);
    __shared__ float sw[4];
    if ((t & 63) == 0) sw[t >> 6] = ss;
    __syncthreads();
    float tot = sw[0] + sw[1] + sw[2] + sw[3];
    float sc = rsqrtf(tot * (1.0f / 512.0f) + 1.1920929e-07f);
    float o0 = v0 * sc * ldin(nw, t, isbf);
    float o1 = v1 * sc * ldin(nw, 256 + t, isbf);
    unsigned short hh, ll;
    split2(o0, hh, ll); xnh[base + t] = hh;       xnl[base + t] = ll;
    split2(o1, hh, ll); xnh[base + 256 + t] = hh; xnl[base + 256 + t] = ll;
}

// ------- causal depthwise conv (k=4) + SiLU -> fp32 u + pre-split bf16 ------
// Coalesced: cwT[l][k][e] and cbF are fp32, stride-1 across lanes.
__global__ __launch_bounds__(256) void conv_silu_k(
    const float* __restrict__ xz,
    const float* __restrict__ cwT, long cwoff,
    const float* __restrict__ cbF, long cboff,
    float* __restrict__ xi,
    unsigned short* __restrict__ xih, unsigned short* __restrict__ xil)
{
    int g = blockIdx.x * 256 + threadIdx.x;   // T*E = 2M
    int e = g & 1023;
    int l = (g >> 10) & 1023;
    int b = g >> 20;
    float acc = cbF[cboff + e];
#pragma unroll
    for (int k = 0; k < 4; ++k) {
        int ls = l - 3 + k;
        if (ls >= 0)
            acc += cwT[cwoff + k * 1024 + e] *
                   xz[((size_t)(b * 1024 + ls)) * 2048 + e];
    }
    acc = acc / (1.f + __expf(-acc));         // SiLU
    xi[g] = acc;
    unsigned short hh, ll;
    split2(acc, hh, ll);
    xih[g] = hh; xil[g] = ll;
}

// --------------------- selective scan, chunked (64 x 16) --------------------
#define CL 16
#define NCH 64

// Fused: split-K reduce of x_proj partials -> dbc; dt_proj (fp32 VALU dot,
// coalesced k-major weights) + bias + softplus -> dtf; chunk scan -> S, Dsum.
__global__ __launch_bounds__(256, 1) void xp_dt_scan1(
    const float* __restrict__ Pxp,
    const float* __restrict__ dtwT, long dtwoff,
    const void* __restrict__ dtb, long dtboff,
    const float* __restrict__ AenT, long aoff,
    const float* __restrict__ xi,
    const int* __restrict__ flag,
    float* __restrict__ dbc, float* __restrict__ dtf,
    float* __restrict__ S, float* __restrict__ Dsum)
{
    const int isbf = *flag;
    const int tid = threadIdx.x;
    const int c = blockIdx.x, eg = blockIdx.y, b = blockIdx.z;
    const int t0 = b * 1024 + c * CL;

    __shared__ float red[CL][64];             // reduced dbc rows for this chunk

    // Phase A: reduce Pxp (8 z-slices) for 16 rows x 64 cols.
    for (int idx = tid; idx < CL * 64; idx += 256) {
        int ti = idx >> 6, n = idx & 63;
        float s = 0.f;
#pragma unroll
        for (int z = 0; z < 8; ++z)
            s += Pxp[(size_t)z * 131072 + (size_t)(t0 + ti) * 64 + n];
        red[ti][n] = s;
        if (eg == 0) dbc[(size_t)(t0 + ti) * 64 + n] = s;
    }

    const int e = eg * 256 + tid;

    // Batch preloads (coalesced; independent of red, overlap with Phase A).
    float wk[32];
#pragma unroll
    for (int k = 0; k < 32; ++k) wk[k] = dtwT[dtwoff + (size_t)k * 1024 + e];
    const float bias = ldin(dtb, dtboff + e, isbf);
    float Aen[16];
#pragma unroll
    for (int n = 0; n < 16; ++n) Aen[n] = AenT[aoff + (size_t)n * 1024 + e];
    float uv[CL];
#pragma unroll
    for (int i = 0; i < CL; ++i) uv[i] = xi[(size_t)(t0 + i) * 1024 + e];

    __syncthreads();

    // Phase B+C: per time-step dt dot (fp32) then scan update.
    float Sn[16];
#pragma unroll
    for (int n = 0; n < 16; ++n) Sn[n] = 0.f;
    float ds = 0.f;
#pragma unroll
    for (int i = 0; i < CL; ++i) {
        const float4* rp = (const float4*)&red[i][0];
        float acc = bias;
#pragma unroll
        for (int k4 = 0; k4 < 8; ++k4) {
            float4 r4 = rp[k4];
            acc += r4.x * wk[k4 * 4 + 0] + r4.y * wk[k4 * 4 + 1]
                 + r4.z * wk[k4 * 4 + 2] + r4.w * wk[k4 * 4 + 3];
        }
        float d = softplus_f(acc);
        dtf[(size_t)(t0 + i) * 1024 + e] = d;
        ds += d;
        float du = d * uv[i];
        const float4* Bp = (const float4*)&red[i][32];
        float4 b0 = Bp[0], b1 = Bp[1], b2 = Bp[2], b3 = Bp[3];
        float Bt[16] = {b0.x,b0.y,b0.z,b0.w, b1.x,b1.y,b1.z,b1.w,
                        b2.x,b2.y,b2.z,b2.w, b3.x,b3.y,b3.z,b3.w};
#pragma unroll
        for (int n = 0; n < 16; ++n) {
            float a = __expf(d * Aen[n]);
            Sn[n] = a * Sn[n] + du * Bt[n];
        }
    }
    size_t ob = ((size_t)(b * NCH + c) * 16) * 1024 + e;
#pragma unroll
    for (int n = 0; n < 16; ++n) S[ob + (size_t)n * 1024] = Sn[n];
    Dsum[(size_t)(b * NCH + c) * 1024 + e] = ds;
}

// cross-chunk combine: decay recomputed from Dsum (one exp per step).
__global__ __launch_bounds__(256, 1) void scan_stage2(
    const float* __restrict__ S, const float* __restrict__ Dsum,
    const float* __restrict__ AenT, long aoff,
    float* __restrict__ H0)
{
    int g = blockIdx.x * 256 + threadIdx.x;   // 32768: e + 1024n + 16384b
    int e = g & 1023, n = (g >> 10) & 15, b = g >> 14;
    const float Aen = AenT[aoff + (size_t)n * 1024 + e];
    float H = 0.f;
    for (int cb = 0; cb < NCH; cb += 8) {
        float s[8], pj[8];
#pragma unroll
        for (int j = 0; j < 8; ++j) {
            size_t idx = ((size_t)(b * NCH + cb + j) * 16 + n) * 1024 + e;
            s[j] = S[idx];
            pj[j] = __expf(Dsum[(size_t)(b * NCH + cb + j) * 1024 + e] * Aen);
        }
#pragma unroll
        for (int j = 0; j < 8; ++j) {
            size_t idx = ((size_t)(b * NCH + cb + j) * 16 + n) * 1024 + e;
            H0[idx] = H;
            H = pj[j] * H + s[j];
        }
    }
}

// final sweep: y = sum_n C*h + u*D, gate with silu(z); emit pre-split bf16.
__global__ __launch_bounds__(256, 1) void scan_stage3(
    const float* __restrict__ dtp, const float* __restrict__ u,
    const float* __restrict__ dbc,
    const float* __restrict__ AenT, long aoff,
    const void* __restrict__ Dv, long doff,
    const int* __restrict__ flag,
    const float* __restrict__ xz, const float* __restrict__ H0,
    unsigned short* __restrict__ yh, unsigned short* __restrict__ yl)
{
    const int isbf = *flag;
    int g = blockIdx.x * 256 + threadIdx.x;   // 131072
    int e = g & 1023, c = (g >> 10) & (NCH - 1), b = g >> 16;
    int t0 = b * 1024 + c * CL;

    float dv[CL], uv[CL], zv[CL];
#pragma unroll
    for (int i = 0; i < CL; ++i) {
        dv[i] = dtp[(size_t)(t0 + i) * 1024 + e];
        uv[i] = u[(size_t)(t0 + i) * 1024 + e];
        zv[i] = xz[(size_t)(t0 + i) * 2048 + 1024 + e];
    }

    float Aen[16], h[16];
    size_t ob = ((size_t)(b * NCH + c) * 16) * 1024 + e;
#pragma unroll
    for (int n = 0; n < 16; ++n) {
        Aen[n] = AenT[aoff + (size_t)n * 1024 + e];
        h[n] = H0[ob + (size_t)n * 1024];
    }
    float De = ldin(Dv, doff + e, isbf);
#pragma unroll
    for (int i = 0; i < CL; ++i) {
        float d = dv[i], uu = uv[i], du = d * uu;
        const float4* Bp = (const float4*)(dbc + (size_t)(t0 + i) * 64 + 32);
        float4 b0 = Bp[0], b1 = Bp[1], b2 = Bp[2], b3 = Bp[3];
        float4 c0 = Bp[4], c1 = Bp[5], c2 = Bp[6], c3 = Bp[7];
        float Bt[16] = {b0.x,b0.y,b0.z,b0.w, b1.x,b1.y,b1.z,b1.w,
                        b2.x,b2.y,b2.z,b2.w, b3.x,b3.y,b3.z,b3.w};
        float Ct[16] = {c0.x,c0.y,c0.z,c0.w, c1.x,c1.y,c1.z,c1.w,
                        c2.x,c2.y,c2.z,c2.w, c3.x,c3.y,c3.z,c3.w};
        float y = 0.f;
#pragma unroll
        for (int n = 0; n < 16; ++n) {
            float a = __expf(d * Aen[n]);
            h[n] = a * h[n] + du * Bt[n];
            y += h[n] * Ct[n];
        }
        float sz = zv[i] / (1.f + __expf(-zv[i]));
        float yv = (y + uu * De) * sz;
        unsigned short hh, ll;
        split2(yv, hh, ll);
        yh[(size_t)(t0 + i) * 1024 + e] = hh;
        yl[(size_t)(t0 + i) * 1024 + e] = ll;
    }
}

// ------------------------------- launcher -----------------------------------
extern "C" void kernel_launch(void* const* d_in, const int* in_sizes, int n_in,
                              void* d_out, int out_size, void* d_ws, size_t ws_size,
                              hipStream_t stream)
{
    const void* x    = d_in[0];
    const void* pos  = d_in[1];
    const void* nw   = d_in[2];
    const void* ipw  = d_in[3];   // (6,2048,512)
    const void* cw   = d_in[4];   // (6,1024,4)
    const void* cb   = d_in[5];   // (6,1024)
    const void* xpw  = d_in[6];   // (6,64,1024)
    const void* dtw  = d_in[7];   // (6,1024,32)
    const void* dtb  = d_in[8];   // (6,1024)
    const void* alog = d_in[9];   // (6,1024,16)
    const void* Dw   = d_in[10];  // (6,1024)
    const void* ow   = d_in[11];  // (6,512,1024)

    char* w = (char*)d_ws;
    auto take = [&](size_t bytes) { char* p = w; w += (bytes + 255) & ~255ull; return p; };

    float* h    = (float*)take(2048ull * 512 * 4);
    float* xz   = (float*)take(2048ull * 2048 * 4);
    float* xi   = (float*)take(2048ull * 1024 * 4);
    float* dtf  = (float*)take(2048ull * 1024 * 4);
    float* dbc  = (float*)take(2048ull * 64 * 4);
    float* S    = (float*)take(2ull * NCH * 16 * 1024 * 4);   // 8 MB
    float* H0   = (float*)take(2ull * NCH * 16 * 1024 * 4);   // 8 MB
    float* Dsum = (float*)take(2ull * NCH * 1024 * 4);        // 0.5 MB
    float* Pxp  = (float*)take(8ull * 2048 * 64 * 4);
    float* dtwT = (float*)take(6ull * 32 * 1024 * 4);
    float* AenT = (float*)take(6ull * 16 * 1024 * 4);
    float* cwT  = (float*)take(6ull * 4 * 1024 * 4);
    float* cbF  = (float*)take(6ull * 1024 * 4);
    unsigned short* xnh = (unsigned short*)take(2048ull * 512 * 2);
    unsigned short* xnl = (unsigned short*)take(2048ull * 512 * 2);
    unsigned short* xih = (unsigned short*)take(2048ull * 1024 * 2);
    unsigned short* xil = (unsigned short*)take(2048ull * 1024 * 2);
    unsigned short* yh  = (unsigned short*)take(2048ull * 1024 * 2);
    unsigned short* yl  = (unsigned short*)take(2048ull * 1024 * 2);
    unsigned short* wip_h = (unsigned short*)take(6ull * 2048 * 512 * 2);
    unsigned short* wip_l = (unsigned short*)take(6ull * 2048 * 512 * 2);
    unsigned short* wow_h = (unsigned short*)take(6ull * 512 * 1024 * 2);
    unsigned short* wow_l = (unsigned short*)take(6ull * 512 * 1024 * 2);
    unsigned short* wxp_h = (unsigned short*)take(6ull * 64 * 1024 * 2);
    unsigned short* wxp_l = (unsigned short*)take(6ull * 64 * 1024 * 2);
    int* flag = (int*)take(256);

    wsplit_all<<<(S1 + S2 + S3 + S4 + S5 + S6 + S7 + 255) / 256, 256, 0, stream>>>(
        ipw, ow, xpw, dtw, alog, cw, cb, Dw,
        wip_h, wip_l, wow_h, wow_l, wxp_h, wxp_l, dtwT, AenT, cwT, cbF, flag);

    for (int l = 0; l < 6; ++l) {
        // rmsnorm(h + pos): layer 0 reads x (dynamic dtype), else fp32 h
        rmsnorm_k<<<2048, 256, 0, stream>>>(
            l == 0 ? x : (const void*)h, l == 0 ? 1 : 0, pos, nw, flag, xnh, xnl);
        // in_proj: 128x128 tiles, 8 waves, XCD-swizzled 1D grid
        gemm128<<<256, 512, 0, stream>>>(
            xnh, xnl, 512, wip_h, wip_l, (long)l * 2048 * 512, xz, 2048, 512);
        conv_silu_k<<<8192, 256, 0, stream>>>(xz, cwT, (long)l * 4096, cbF, (long)l * 1024,
                                              xi, xih, xil);
        // x_proj: (T,1024) x (64,1024)^T, split-K x8 -> Pxp, 8 waves, dbuf
        gemm_hl<0, 0><<<dim3(32, 1, 8), 512, 0, stream>>>(
            xih, xil, 1024, wxp_h, wxp_l, (long)l * 64 * 1024,
            Pxp, 2048l * 64, nullptr, 0, flag, 64, 1024, 128);
        // fused: reduce + dt_proj(fp32) + chunk scan -> dbc, dtf, S, Dsum
        xp_dt_scan1<<<dim3(NCH, 4, 2), 256, 0, stream>>>(
            Pxp, dtwT, (long)l * 32768, dtb, (long)l * 1024,
            AenT, (long)l * 16384, xi, flag, dbc, dtf, S, Dsum);
        scan_stage2<<<128, 256, 0, stream>>>(S, Dsum, AenT, (long)l * 16384, H0);
        scan_stage3<<<512, 256, 0, stream>>>(dtf, xi, dbc, AenT, (long)l * 16384,
                                             Dw, (long)l * 1024, flag, xz, H0, yh, yl);
        // out_proj: 8 waves, dbuf, XCD-swizzled 1D grid (32m x 8n tiles)
        float* outp = (l < 5) ? h : (float*)d_out;
        gemm_hl<0, 1><<<256, 512, 0, stream>>>(
            yh, yl, 1024, wow_h, wow_l, (long)l * 512 * 1024,
            outp, 0, nullptr, 0, flag, 512, 1024, 1024);
    }
}